// Round 2
// baseline (878.843 us; speedup 1.0000x reference)
//
#include <hip/hip_runtime.h>
#include <hip/hip_bf16.h>
#include <cstdint>

// Problem constants (B=2,S=4096,D=2048,E=8,SH=2,F=512,K=2)
#define TOKENS   8192
#define D_DIM    2048
#define F_DIM    512
#define NE       8
#define NSH      2
#define NZ       10
#define OUT_ELEMS (TOKENS * D_DIM)

// pair bookkeeping: routed capacity tile-padded, then shared pairs
#define RCAP     17408                  // sum ceil(c_e/128)*128 <= 16384+8*127 -> 17408
#define SH_BASE  RCAP
#define NPAIRS   (RCAP + 2 * TOKENS)    // 33792
#define MAX_RT   136                    // max routed M-tiles
#define NTILES   264                    // 136 routed (max) + 2*64 shared

typedef __attribute__((ext_vector_type(8))) short bf16x8;
typedef __attribute__((ext_vector_type(4))) float f32x4;

__device__ __forceinline__ short f2bf(float f) {
  union { float f; uint32_t u; } v; v.f = f;
  uint32_t r = (v.u + 0x7fffu + ((v.u >> 16) & 1u)) >> 16;
  return (short)r;
}

__device__ __forceinline__ void gload_lds16(const void* g, void* l) {
  __builtin_amdgcn_global_load_lds(
      (const __attribute__((address_space(1))) unsigned int*)g,
      (__attribute__((address_space(3))) unsigned int*)l,
      16, 0, 0);
}

// ---------------- convert fp32 -> bf16 -------------------------------------
__global__ void k_convert(const float* __restrict__ in, short* __restrict__ out, int n4) {
  int i = blockIdx.x * blockDim.x + threadIdx.x;
  int stride = gridDim.x * blockDim.x;
  for (; i < n4; i += stride) {
    float4 v = ((const float4*)in)[i];
    short4 o;
    o.x = f2bf(v.x); o.y = f2bf(v.y); o.z = f2bf(v.z); o.w = f2bf(v.w);
    ((short4*)out)[i] = o;
  }
}

// ------------- transpose-convert fp32 (R,C) -> bf16 (C,R), batched ----------
__global__ void k_transpose(const float* __restrict__ in, short* __restrict__ out,
                            int R, int C) {
  __shared__ float tile[32][33];
  int b = blockIdx.z;
  in  += (size_t)b * R * C;
  out += (size_t)b * R * C;
  int c0 = blockIdx.x * 32, r0 = blockIdx.y * 32;
  #pragma unroll
  for (int i = 0; i < 32; i += 8) {
    int r = r0 + threadIdx.y + i, c = c0 + threadIdx.x;
    tile[threadIdx.y + i][threadIdx.x] = in[(size_t)r * C + c];
  }
  __syncthreads();
  #pragma unroll
  for (int i = 0; i < 32; i += 8) {
    int c = c0 + threadIdx.y + i, r = r0 + threadIdx.x;
    out[(size_t)c * R + r] = f2bf(tile[threadIdx.x][threadIdx.y + i]);
  }
}

// ---------------- zero pad region of pair arrays ----------------------------
__global__ void k_init(int* __restrict__ pair_tok, float* __restrict__ pair_gate) {
  int i = blockIdx.x * blockDim.x + threadIdx.x;
  if (i < RCAP) { pair_tok[i] = 0; pair_gate[i] = 0.f; }
}

// ---------------- router: wave-per-token, fp32, exact top-2 -----------------
__global__ __launch_bounds__(256) void k_router(
    const float* __restrict__ x, const float* __restrict__ rw,
    const float* __restrict__ rb, int2* __restrict__ ti, float2* __restrict__ tg) {
  int wave = threadIdx.x >> 6;
  int lane = threadIdx.x & 63;
  int t = blockIdx.x * 4 + wave;
  const float* xr = x + (size_t)t * D_DIM;
  float acc[NE];
  #pragma unroll
  for (int e = 0; e < NE; e++) acc[e] = 0.f;
  for (int d = lane; d < D_DIM; d += 64) {
    float xv = xr[d];
    #pragma unroll
    for (int e = 0; e < NE; e++) acc[e] += xv * rw[e * D_DIM + d];
  }
  #pragma unroll
  for (int e = 0; e < NE; e++) {
    #pragma unroll
    for (int off = 32; off > 0; off >>= 1) acc[e] += __shfl_xor(acc[e], off);
  }
  if (lane == 0) {
    float lg[NE];
    #pragma unroll
    for (int e = 0; e < NE; e++) lg[e] = acc[e] + rb[e];
    int i0 = 0;
    #pragma unroll
    for (int e = 1; e < NE; e++) if (lg[e] > lg[i0]) i0 = e;
    int i1 = (i0 == 0) ? 1 : 0;
    #pragma unroll
    for (int e = 0; e < NE; e++) if (e != i0 && e != i1 && lg[e] > lg[i1]) i1 = e;
    float e1 = __expf(lg[i1] - lg[i0]);
    float inv = 1.f / (1.f + e1);
    ti[t] = make_int2(i0, i1);
    tg[t] = make_float2(inv, e1 * inv);
  }
}

// ------------- count + segment bases + tile table (single block) ------------
// meta: [0..7]=counts [8..15]=cursor [16..17]=loss counts [18]=n_routed_tiles
//       [19..26]=seg_base
__global__ __launch_bounds__(1024) void k_count(
    const int2* __restrict__ ti, int* __restrict__ meta,
    int* __restrict__ tile_z, int* __restrict__ tile_row) {
  __shared__ int cnt[NE + 2];
  if (threadIdx.x < NE + 2) cnt[threadIdx.x] = 0;
  __syncthreads();
  int loc[NE]; int l0 = 0, l1 = 0;
  #pragma unroll
  for (int e = 0; e < NE; e++) loc[e] = 0;
  for (int t = threadIdx.x; t < TOKENS; t += 1024) {
    int2 ii = ti[t];
    loc[ii.x]++; loc[ii.y]++;
    l0 += (ii.x == 0); l1 += (ii.y == 1);
  }
  #pragma unroll
  for (int e = 0; e < NE; e++) if (loc[e]) atomicAdd(&cnt[e], loc[e]);
  if (l0) atomicAdd(&cnt[NE], l0);
  if (l1) atomicAdd(&cnt[NE + 1], l1);
  __syncthreads();
  if (threadIdx.x == 0) {
    int base = 0, nrt = 0;
    #pragma unroll
    for (int e = 0; e < NE; e++) {
      int c = cnt[e];
      meta[e] = c;
      meta[19 + e] = base;
      meta[8 + e] = 0;                       // cursor
      int nt = (c + 127) >> 7;
      for (int i = 0; i < nt; i++) { tile_z[nrt] = e; tile_row[nrt] = base + i * 128; nrt++; }
      base += nt * 128;
    }
    meta[16] = cnt[NE]; meta[17] = cnt[NE + 1];
    meta[18] = nrt;
    for (int i = 0; i < 128; i++) {          // shared tiles at fixed slots
      tile_z[MAX_RT + i] = NE + (i >> 6);
      tile_row[MAX_RT + i] = SH_BASE + i * 128;
    }
  }
}

// ---------------- assignment: ballot-scan within wave -----------------------
__global__ __launch_bounds__(256) void k_assign(
    const int2* __restrict__ ti, const float2* __restrict__ tg,
    int* __restrict__ meta, int* __restrict__ pair_tok, float* __restrict__ pair_gate) {
  int t = blockIdx.x * 256 + threadIdx.x;
  int lane = threadIdx.x & 63;
  int2 ii = ti[t];
  float2 gg = tg[t];
  unsigned long long below = (1ull << lane) - 1ull;
  #pragma unroll
  for (int e = 0; e < NE; e++) {
    unsigned long long m0 = __ballot(ii.x == e);
    unsigned long long m1 = __ballot(ii.y == e);
    unsigned c = __popcll(m0) + __popcll(m1);
    unsigned base = 0;
    if (lane == 0 && c) base = atomicAdd((unsigned*)&meta[8 + e], c);
    base = __shfl((int)base, 0);
    int seg = meta[19 + e];
    if (ii.x == e) {
      int p = seg + base + __popcll(m0 & below);
      pair_tok[p] = t; pair_gate[p] = gg.x;
    }
    if (ii.y == e) {
      int p = seg + base + __popcll(m0) + __popcll(m1 & below);
      pair_tok[p] = t; pair_gate[p] = gg.y;
    }
  }
  // shared pairs: fixed positions
  pair_tok[SH_BASE + t] = t;            pair_gate[SH_BASE + t] = 1.f;
  pair_tok[SH_BASE + TOKENS + t] = t;   pair_gate[SH_BASE + TOKENS + t] = 1.f;
}

// ---------------- aux loss --------------------------------------------------
__global__ void k_loss(const int* __restrict__ meta, float* __restrict__ out_loss) {
  if (threadIdx.x == 0 && blockIdx.x == 0) {
    float p0 = (float)meta[16] / 16384.0f + 1e-8f;
    float p1 = (float)meta[17] / 16384.0f + 1e-8f;
    float rest = 6.0f * (1e-8f * logf(1e-8f));
    out_loss[0] = -(p0 * logf(p0) + p1 * logf(p1) + rest);
  }
}

// ---------------- out = all bias terms --------------------------------------
__global__ __launch_bounds__(256) void k_initout(
    const int2* __restrict__ ti, const float2* __restrict__ tg,
    const float* __restrict__ eb2, const float* __restrict__ sb2,
    float* __restrict__ out) {
  int idx = blockIdx.x * 256 + threadIdx.x;       // over OUT_ELEMS/4
  int t = idx >> 9, c4 = idx & 511;
  int col = c4 * 4;
  int2 ii = ti[t]; float2 gg = tg[t];
  float4 a = *(const float4*)&eb2[(size_t)ii.x * D_DIM + col];
  float4 b = *(const float4*)&eb2[(size_t)ii.y * D_DIM + col];
  float4 s0 = *(const float4*)&sb2[col];
  float4 s1 = *(const float4*)&sb2[D_DIM + col];
  float4 r;
  r.x = gg.x * a.x + gg.y * b.x + s0.x + s1.x;
  r.y = gg.x * a.y + gg.y * b.y + s0.y + s1.y;
  r.z = gg.x * a.z + gg.y * b.z + s0.z + s1.z;
  r.w = gg.x * a.w + gg.y * b.w + s0.w + s1.w;
  *(float4*)&out[(size_t)idx * 4] = r;
}

// ---------------- GEMM1 (grouped): H[p] = gelu(x[tok(p)]@W1[z]+b1)*gate -----
// LDS layout (conflict-free, linear dest for global_load_lds):
//   chunk(row,c8) at shorts offset rg*1024 + c8*128 + (row&15)*8, rg=row>>4
// fragment read: &As[(wgrp*4+m)*1024 + kk*16 + lane*8]  (1KB contiguous/wave)
__global__ __launch_bounds__(256) void k_gemm1(
    const short* __restrict__ xb, const short* __restrict__ w1t,
    const float* __restrict__ eb1, const float* __restrict__ sb1,
    const int* __restrict__ meta, const int* __restrict__ tile_z,
    const int* __restrict__ tile_row, const int* __restrict__ pair_tok,
    const float* __restrict__ pair_gate, short* __restrict__ H) {
  const int bt = blockIdx.x;
  if (bt < MAX_RT && bt >= meta[18]) return;      // inactive routed tile
  const int z = tile_z[bt];
  const int row0 = tile_row[bt];
  const int bn = blockIdx.y;
  __shared__ __align__(16) short As[128 * 64];
  __shared__ __align__(16) short Bs[128 * 64];
  const int tid = threadIdx.x;
  const int lane = tid & 63;
  const int wv = tid >> 6;
  const int wm = wv >> 1, wn = wv & 1;
  const short* Bbase = w1t + (size_t)z * F_DIM * D_DIM;

  // per-thread staging geometry (4 chunks): id=i*256+tid
  int srow[4], scoff[4], stok[4];
  #pragma unroll
  for (int i = 0; i < 4; i++) {
    int id = i * 256 + tid;
    srow[i] = ((id >> 7) << 4) | (id & 15);
    scoff[i] = ((id >> 4) & 7) * 8;
    stok[i] = pair_tok[row0 + srow[i]];
  }

  f32x4 acc[4][4];
  #pragma unroll
  for (int m = 0; m < 4; m++)
    #pragma unroll
    for (int n = 0; n < 4; n++) acc[m][n] = (f32x4)(0.f);

  for (int k0 = 0; k0 < D_DIM; k0 += 64) {
    #pragma unroll
    for (int i = 0; i < 4; i++) {
      int id = i * 256 + tid;
      gload_lds16(xb    + (size_t)stok[i] * D_DIM + k0 + scoff[i], &As[id * 8]);
      gload_lds16(Bbase + (size_t)(bn * 128 + srow[i]) * D_DIM + k0 + scoff[i], &Bs[id * 8]);
    }
    __syncthreads();
    #pragma unroll
    for (int kk = 0; kk < 64; kk += 32) {
      bf16x8 af[4], bfr[4];
      #pragma unroll
      for (int m = 0; m < 4; m++)
        af[m] = *(const bf16x8*)&As[(wm * 4 + m) * 1024 + kk * 16 + lane * 8];
      #pragma unroll
      for (int n = 0; n < 4; n++)
        bfr[n] = *(const bf16x8*)&Bs[(wn * 4 + n) * 1024 + kk * 16 + lane * 8];
      #pragma unroll
      for (int m = 0; m < 4; m++)
        #pragma unroll
        for (int n = 0; n < 4; n++)
          acc[m][n] = __builtin_amdgcn_mfma_f32_16x16x32_bf16(af[m], bfr[n], acc[m][n], 0, 0, 0);
    }
    __syncthreads();
  }

  const float* b1 = (z < NE) ? (eb1 + z * F_DIM) : (sb1 + (size_t)(z - NE) * F_DIM);
  #pragma unroll
  for (int m = 0; m < 4; m++) {
    #pragma unroll
    for (int r = 0; r < 4; r++) {
      int rl = wm * 64 + m * 16 + (lane >> 4) * 4 + r;
      float g = pair_gate[row0 + rl];
      #pragma unroll
      for (int n = 0; n < 4; n++) {
        int col = bn * 128 + wn * 64 + n * 16 + (lane & 15);
        float c = acc[m][n][r] + b1[col];
        float h = 0.5f * c * (1.0f + erff(c * 0.70710678118654752440f));
        H[(size_t)(row0 + rl) * F_DIM + col] = f2bf(h * g);
      }
    }
  }
}

// ---------------- GEMM2 (grouped): out[tok(p)] += H[p] @ W2t[z] -------------
__global__ __launch_bounds__(256) void k_gemm2(
    const short* __restrict__ H, const short* __restrict__ w2t,
    const int* __restrict__ meta, const int* __restrict__ tile_z,
    const int* __restrict__ tile_row, const int* __restrict__ pair_tok,
    float* __restrict__ out) {
  const int bt = blockIdx.x;
  if (bt < MAX_RT && bt >= meta[18]) return;
  const int z = tile_z[bt];
  const int row0 = tile_row[bt];
  const int bn = blockIdx.y;
  __shared__ __align__(16) short As[128 * 64];
  __shared__ __align__(16) short Bs[128 * 64];
  const int tid = threadIdx.x;
  const int lane = tid & 63;
  const int wv = tid >> 6;
  const int wm = wv >> 1, wn = wv & 1;
  const short* Bbase = w2t + (size_t)z * D_DIM * F_DIM;

  int srow[4], scoff[4];
  #pragma unroll
  for (int i = 0; i < 4; i++) {
    int id = i * 256 + tid;
    srow[i] = ((id >> 7) << 4) | (id & 15);
    scoff[i] = ((id >> 4) & 7) * 8;
  }

  f32x4 acc[4][4];
  #pragma unroll
  for (int m = 0; m < 4; m++)
    #pragma unroll
    for (int n = 0; n < 4; n++) acc[m][n] = (f32x4)(0.f);

  for (int f0 = 0; f0 < F_DIM; f0 += 64) {
    #pragma unroll
    for (int i = 0; i < 4; i++) {
      int id = i * 256 + tid;
      gload_lds16(H     + (size_t)(row0 + srow[i]) * F_DIM + f0 + scoff[i], &As[id * 8]);
      gload_lds16(Bbase + (size_t)(bn * 128 + srow[i]) * F_DIM + f0 + scoff[i], &Bs[id * 8]);
    }
    __syncthreads();
    #pragma unroll
    for (int kk = 0; kk < 64; kk += 32) {
      bf16x8 af[4], bfr[4];
      #pragma unroll
      for (int m = 0; m < 4; m++)
        af[m] = *(const bf16x8*)&As[(wm * 4 + m) * 1024 + kk * 16 + lane * 8];
      #pragma unroll
      for (int n = 0; n < 4; n++)
        bfr[n] = *(const bf16x8*)&Bs[(wn * 4 + n) * 1024 + kk * 16 + lane * 8];
      #pragma unroll
      for (int m = 0; m < 4; m++)
        #pragma unroll
        for (int n = 0; n < 4; n++)
          acc[m][n] = __builtin_amdgcn_mfma_f32_16x16x32_bf16(af[m], bfr[n], acc[m][n], 0, 0, 0);
    }
    __syncthreads();
  }

  #pragma unroll
  for (int m = 0; m < 4; m++) {
    #pragma unroll
    for (int r = 0; r < 4; r++) {
      int rl = wm * 64 + m * 16 + (lane >> 4) * 4 + r;
      int tok = pair_tok[row0 + rl];
      #pragma unroll
      for (int n = 0; n < 4; n++) {
        int col = bn * 128 + wn * 64 + n * 16 + (lane & 15);
        atomicAdd(&out[(size_t)tok * D_DIM + col], acc[m][n][r]);
      }
    }
  }
}

// ---------------------------------------------------------------------------
extern "C" void kernel_launch(void* const* d_in, const int* in_sizes, int n_in,
                              void* d_out, int out_size, void* d_ws, size_t ws_size,
                              hipStream_t stream) {
  (void)in_sizes; (void)n_in; (void)out_size; (void)ws_size;
  const float* x        = (const float*)d_in[0];
  const float* router_w = (const float*)d_in[1];
  const float* router_b = (const float*)d_in[2];
  const float* ew1      = (const float*)d_in[3];
  const float* eb1      = (const float*)d_in[4];
  const float* ew2      = (const float*)d_in[5];
  const float* eb2      = (const float*)d_in[6];
  const float* sw1      = (const float*)d_in[7];
  const float* sb1      = (const float*)d_in[8];
  const float* sw2      = (const float*)d_in[9];
  const float* sb2      = (const float*)d_in[10];
  float* out = (float*)d_out;

  char* ws = (char*)d_ws;
  short* xb   = (short*)ws;                                   // 33,554,432 B
  short* w1t  = xb  + (size_t)TOKENS * D_DIM;                 // 20,971,520 B
  short* w2t  = w1t + (size_t)NZ * F_DIM * D_DIM;             // 20,971,520 B
  short* Hbuf = w2t + (size_t)NZ * D_DIM * F_DIM;             // 34,603,008 B
  int2*   ti        = (int2*)(Hbuf + (size_t)NPAIRS * F_DIM);
  float2* tg        = (float2*)(ti + TOKENS);
  int*    pair_tok  = (int*)(tg + TOKENS);
  float*  pair_gate = (float*)(pair_tok + NPAIRS);
  int*    meta      = (int*)(pair_gate + NPAIRS);
  int*    tile_z    = meta + 32;
  int*    tile_row  = tile_z + NTILES;

  k_convert<<<2048, 256, 0, stream>>>(x, xb, TOKENS * D_DIM / 4);
  k_transpose<<<dim3(F_DIM / 32, D_DIM / 32, NE),  dim3(32, 8), 0, stream>>>(ew1, w1t, D_DIM, F_DIM);
  k_transpose<<<dim3(F_DIM / 32, D_DIM / 32, NSH), dim3(32, 8), 0, stream>>>(sw1, w1t + (size_t)NE * F_DIM * D_DIM, D_DIM, F_DIM);
  k_transpose<<<dim3(D_DIM / 32, F_DIM / 32, NE),  dim3(32, 8), 0, stream>>>(ew2, w2t, F_DIM, D_DIM);
  k_transpose<<<dim3(D_DIM / 32, F_DIM / 32, NSH), dim3(32, 8), 0, stream>>>(sw2, w2t + (size_t)NE * D_DIM * F_DIM, F_DIM, D_DIM);

  k_init<<<(RCAP + 255) / 256, 256, 0, stream>>>(pair_tok, pair_gate);
  k_router<<<TOKENS / 4, 256, 0, stream>>>(x, router_w, router_b, ti, tg);
  k_count<<<1, 1024, 0, stream>>>(ti, meta, tile_z, tile_row);
  k_assign<<<TOKENS / 256, 256, 0, stream>>>(ti, tg, meta, pair_tok, pair_gate);
  k_loss<<<1, 64, 0, stream>>>(meta, out + OUT_ELEMS);
  k_initout<<<OUT_ELEMS / 4 / 256, 256, 0, stream>>>(ti, tg, eb2, sb2, out);

  k_gemm1<<<dim3(NTILES, F_DIM / 128), 256, 0, stream>>>(
      xb, w1t, eb1, sb1, meta, tile_z, tile_row, pair_tok, pair_gate, Hbuf);
  k_gemm2<<<dim3(NTILES, D_DIM / 128), 256, 0, stream>>>(
      Hbuf, w2t, meta, tile_z, tile_row, pair_tok, out);
}

// Round 3
// 567.668 us; speedup vs baseline: 1.5482x; 1.5482x over previous
//
#include <hip/hip_runtime.h>
#include <hip/hip_bf16.h>
#include <cstdint>

// Problem constants (B=2,S=4096,D=2048,E=8,SH=2,F=512,K=2)
#define TOKENS   8192
#define D_DIM    2048
#define F_DIM    512
#define NE       8
#define NSH      2
#define NZ       10
#define OUT_ELEMS (TOKENS * D_DIM)

// pair bookkeeping: routed capacity tile-padded, then shared pairs
#define RCAP     17408                  // sum ceil(c_e/128)*128 <= 16384+8*127
#define SH_BASE  RCAP
#define NPAIRS   (RCAP + 2 * TOKENS)    // 33792
#define MAX_RT   136                    // max routed M-tiles
#define NTILES   264                    // 136 routed (max) + 2*64 shared (GEMM1)

typedef __attribute__((ext_vector_type(8))) short bf16x8;
typedef __attribute__((ext_vector_type(4))) float f32x4;

__device__ __forceinline__ short f2bf(float f) {
  union { float f; uint32_t u; } v; v.f = f;
  uint32_t r = (v.u + 0x7fffu + ((v.u >> 16) & 1u)) >> 16;
  return (short)r;
}
__device__ __forceinline__ float bf2f(short s) {
  union { float f; uint32_t u; } v; v.u = ((uint32_t)(uint16_t)s) << 16; return v.f;
}

__device__ __forceinline__ void gload_lds16(const void* g, void* l) {
  __builtin_amdgcn_global_load_lds(
      (const __attribute__((address_space(1))) unsigned int*)g,
      (__attribute__((address_space(3))) unsigned int*)l,
      16, 0, 0);
}

// ---------------- convert fp32 -> bf16 -------------------------------------
__global__ void k_convert(const float* __restrict__ in, short* __restrict__ out, int n4) {
  int i = blockIdx.x * blockDim.x + threadIdx.x;
  int stride = gridDim.x * blockDim.x;
  for (; i < n4; i += stride) {
    float4 v = ((const float4*)in)[i];
    short4 o;
    o.x = f2bf(v.x); o.y = f2bf(v.y); o.z = f2bf(v.z); o.w = f2bf(v.w);
    ((short4*)out)[i] = o;
  }
}

// ------------- transpose-convert fp32 (R,C) -> bf16 (C,R), batched ----------
__global__ void k_transpose(const float* __restrict__ in, short* __restrict__ out,
                            int R, int C) {
  __shared__ float tile[32][33];
  int b = blockIdx.z;
  in  += (size_t)b * R * C;
  out += (size_t)b * R * C;
  int c0 = blockIdx.x * 32, r0 = blockIdx.y * 32;
  #pragma unroll
  for (int i = 0; i < 32; i += 8) {
    int r = r0 + threadIdx.y + i, c = c0 + threadIdx.x;
    tile[threadIdx.y + i][threadIdx.x] = in[(size_t)r * C + c];
  }
  __syncthreads();
  #pragma unroll
  for (int i = 0; i < 32; i += 8) {
    int c = c0 + threadIdx.y + i, r = r0 + threadIdx.x;
    out[(size_t)c * R + r] = f2bf(tile[threadIdx.x][threadIdx.y + i]);
  }
}

// ---------------- zero pad region of pair arrays ----------------------------
__global__ void k_init(int* __restrict__ pair_tok, float* __restrict__ pair_gate) {
  int i = blockIdx.x * blockDim.x + threadIdx.x;
  if (i < RCAP) { pair_tok[i] = 0; pair_gate[i] = 0.f; }
}

// ---------------- router: wave-per-token, fp32, exact top-2 -----------------
__global__ __launch_bounds__(256) void k_router(
    const float* __restrict__ x, const float* __restrict__ rw,
    const float* __restrict__ rb, int2* __restrict__ ti, float2* __restrict__ tg) {
  int wave = threadIdx.x >> 6;
  int lane = threadIdx.x & 63;
  int t = blockIdx.x * 4 + wave;
  const float* xr = x + (size_t)t * D_DIM;
  float acc[NE];
  #pragma unroll
  for (int e = 0; e < NE; e++) acc[e] = 0.f;
  for (int d = lane; d < D_DIM; d += 64) {
    float xv = xr[d];
    #pragma unroll
    for (int e = 0; e < NE; e++) acc[e] += xv * rw[e * D_DIM + d];
  }
  #pragma unroll
  for (int e = 0; e < NE; e++) {
    #pragma unroll
    for (int off = 32; off > 0; off >>= 1) acc[e] += __shfl_xor(acc[e], off);
  }
  if (lane == 0) {
    float lg[NE];
    #pragma unroll
    for (int e = 0; e < NE; e++) lg[e] = acc[e] + rb[e];
    int i0 = 0;
    #pragma unroll
    for (int e = 1; e < NE; e++) if (lg[e] > lg[i0]) i0 = e;
    int i1 = (i0 == 0) ? 1 : 0;
    #pragma unroll
    for (int e = 0; e < NE; e++) if (e != i0 && e != i1 && lg[e] > lg[i1]) i1 = e;
    float e1 = __expf(lg[i1] - lg[i0]);
    float inv = 1.f / (1.f + e1);
    ti[t] = make_int2(i0, i1);
    tg[t] = make_float2(inv, e1 * inv);
  }
}

// ------------- count + segment bases + tile table (single block) ------------
// meta: [0..7]=counts [8..15]=cursor [16..17]=loss counts [18]=n_routed_tiles
//       [19..26]=seg_base
__global__ __launch_bounds__(1024) void k_count(
    const int2* __restrict__ ti, int* __restrict__ meta,
    int* __restrict__ tile_z, int* __restrict__ tile_row) {
  __shared__ int cnt[NE + 2];
  if (threadIdx.x < NE + 2) cnt[threadIdx.x] = 0;
  __syncthreads();
  int loc[NE]; int l0 = 0, l1 = 0;
  #pragma unroll
  for (int e = 0; e < NE; e++) loc[e] = 0;
  for (int t = threadIdx.x; t < TOKENS; t += 1024) {
    int2 ii = ti[t];
    loc[ii.x]++; loc[ii.y]++;
    l0 += (ii.x == 0); l1 += (ii.y == 1);
  }
  #pragma unroll
  for (int e = 0; e < NE; e++) if (loc[e]) atomicAdd(&cnt[e], loc[e]);
  if (l0) atomicAdd(&cnt[NE], l0);
  if (l1) atomicAdd(&cnt[NE + 1], l1);
  __syncthreads();
  if (threadIdx.x == 0) {
    int base = 0, nrt = 0;
    #pragma unroll
    for (int e = 0; e < NE; e++) {
      int c = cnt[e];
      meta[e] = c;
      meta[19 + e] = base;
      meta[8 + e] = 0;                       // cursor
      int nt = (c + 127) >> 7;
      for (int i = 0; i < nt; i++) { tile_z[nrt] = e; tile_row[nrt] = base + i * 128; nrt++; }
      base += nt * 128;
    }
    meta[16] = cnt[NE]; meta[17] = cnt[NE + 1];
    meta[18] = nrt;
    for (int i = 0; i < 128; i++) {          // shared tiles (GEMM1 only)
      tile_z[MAX_RT + i] = NE + (i >> 6);
      tile_row[MAX_RT + i] = SH_BASE + i * 128;
    }
  }
}

// ---------------- assignment: ballot-scan within wave + inverse map ---------
__global__ __launch_bounds__(256) void k_assign(
    const int2* __restrict__ ti, const float2* __restrict__ tg,
    int* __restrict__ meta, int* __restrict__ pair_tok, float* __restrict__ pair_gate,
    int2* __restrict__ pos) {
  int t = blockIdx.x * 256 + threadIdx.x;
  int lane = threadIdx.x & 63;
  int2 ii = ti[t];
  float2 gg = tg[t];
  int2 mypos;
  unsigned long long below = (1ull << lane) - 1ull;
  #pragma unroll
  for (int e = 0; e < NE; e++) {
    unsigned long long m0 = __ballot(ii.x == e);
    unsigned long long m1 = __ballot(ii.y == e);
    unsigned c = __popcll(m0) + __popcll(m1);
    unsigned base = 0;
    if (lane == 0 && c) base = atomicAdd((unsigned*)&meta[8 + e], c);
    base = __shfl((int)base, 0);
    int seg = meta[19 + e];
    if (ii.x == e) {
      int p = seg + base + __popcll(m0 & below);
      pair_tok[p] = t; pair_gate[p] = gg.x; mypos.x = p;
    }
    if (ii.y == e) {
      int p = seg + base + __popcll(m0) + __popcll(m1 & below);
      pair_tok[p] = t; pair_gate[p] = gg.y; mypos.y = p;
    }
  }
  pos[t] = mypos;
  pair_tok[SH_BASE + t] = t;            pair_gate[SH_BASE + t] = 1.f;
  pair_tok[SH_BASE + TOKENS + t] = t;   pair_gate[SH_BASE + TOKENS + t] = 1.f;
}

// ---------------- aux loss --------------------------------------------------
__global__ void k_loss(const int* __restrict__ meta, float* __restrict__ out_loss) {
  if (threadIdx.x == 0 && blockIdx.x == 0) {
    float p0 = (float)meta[16] / 16384.0f + 1e-8f;
    float p1 = (float)meta[17] / 16384.0f + 1e-8f;
    float rest = 6.0f * (1e-8f * logf(1e-8f));
    out_loss[0] = -(p0 * logf(p0) + p1 * logf(p1) + rest);
  }
}

// ---------------- GEMM1 (grouped): H[p] = gelu(x[tok(p)]@W1[z]+b1)*gate -----
// LDS layout (conflict-free, linear dest for global_load_lds):
//   chunk(row,c8) at shorts offset (row>>4)*1024 + c8*128 + (row&15)*8
// fragment read: &As[(wgrp*4+m)*1024 + kk*16 + lane*8]  (1KB contiguous/wave)
__global__ __launch_bounds__(256) void k_gemm1(
    const short* __restrict__ xb, const short* __restrict__ w1t,
    const float* __restrict__ eb1, const float* __restrict__ sb1,
    const int* __restrict__ meta, const int* __restrict__ tile_z,
    const int* __restrict__ tile_row, const int* __restrict__ pair_tok,
    const float* __restrict__ pair_gate, short* __restrict__ H) {
  const int bt = blockIdx.x;
  if (bt < MAX_RT && bt >= meta[18]) return;      // inactive routed tile
  const int z = tile_z[bt];
  const int row0 = tile_row[bt];
  const int bn = blockIdx.y;
  __shared__ __align__(16) short As[128 * 64];
  __shared__ __align__(16) short Bs[128 * 64];
  const int tid = threadIdx.x;
  const int lane = tid & 63;
  const int wv = tid >> 6;
  const int wm = wv >> 1, wn = wv & 1;
  const short* Bbase = w1t + (size_t)z * F_DIM * D_DIM;

  int srow[4], scoff[4], stok[4];
  #pragma unroll
  for (int i = 0; i < 4; i++) {
    int id = i * 256 + tid;
    srow[i] = ((id >> 7) << 4) | (id & 15);
    scoff[i] = ((id >> 4) & 7) * 8;
    stok[i] = pair_tok[row0 + srow[i]];
  }

  f32x4 acc[4][4];
  #pragma unroll
  for (int m = 0; m < 4; m++)
    #pragma unroll
    for (int n = 0; n < 4; n++) acc[m][n] = (f32x4)(0.f);

  for (int k0 = 0; k0 < D_DIM; k0 += 64) {
    #pragma unroll
    for (int i = 0; i < 4; i++) {
      int id = i * 256 + tid;
      gload_lds16(xb    + (size_t)stok[i] * D_DIM + k0 + scoff[i], &As[id * 8]);
      gload_lds16(Bbase + (size_t)(bn * 128 + srow[i]) * D_DIM + k0 + scoff[i], &Bs[id * 8]);
    }
    __syncthreads();
    #pragma unroll
    for (int kk = 0; kk < 64; kk += 32) {
      bf16x8 af[4], bfr[4];
      #pragma unroll
      for (int m = 0; m < 4; m++)
        af[m] = *(const bf16x8*)&As[(wm * 4 + m) * 1024 + kk * 16 + lane * 8];
      #pragma unroll
      for (int n = 0; n < 4; n++)
        bfr[n] = *(const bf16x8*)&Bs[(wn * 4 + n) * 1024 + kk * 16 + lane * 8];
      #pragma unroll
      for (int m = 0; m < 4; m++)
        #pragma unroll
        for (int n = 0; n < 4; n++)
          acc[m][n] = __builtin_amdgcn_mfma_f32_16x16x32_bf16(af[m], bfr[n], acc[m][n], 0, 0, 0);
    }
    __syncthreads();
  }

  const float* b1 = (z < NE) ? (eb1 + z * F_DIM) : (sb1 + (size_t)(z - NE) * F_DIM);
  #pragma unroll
  for (int m = 0; m < 4; m++) {
    #pragma unroll
    for (int r = 0; r < 4; r++) {
      int rl = wm * 64 + m * 16 + (lane >> 4) * 4 + r;
      float g = pair_gate[row0 + rl];
      #pragma unroll
      for (int n = 0; n < 4; n++) {
        int col = bn * 128 + wn * 64 + n * 16 + (lane & 15);
        float c = acc[m][n][r] + b1[col];
        float h = 0.5f * c * (1.0f + erff(c * 0.70710678118654752440f));
        H[(size_t)(row0 + rl) * F_DIM + col] = f2bf(h * g);
      }
    }
  }
}

// ---------------- GEMM2 routed: Yr[p] = H[p] @ W2t[z]  (bf16 stores) --------
__global__ __launch_bounds__(256) void k_gemm2r(
    const short* __restrict__ H, const short* __restrict__ w2t,
    const int* __restrict__ meta, const int* __restrict__ tile_z,
    const int* __restrict__ tile_row, short* __restrict__ Yr) {
  const int bt = blockIdx.x;
  if (bt >= meta[18]) return;
  const int z = tile_z[bt];
  const int row0 = tile_row[bt];
  const int bn = blockIdx.y;
  __shared__ __align__(16) short As[128 * 64];
  __shared__ __align__(16) short Bs[128 * 64];
  const int tid = threadIdx.x;
  const int lane = tid & 63;
  const int wv = tid >> 6;
  const int wm = wv >> 1, wn = wv & 1;
  const short* Bbase = w2t + (size_t)z * D_DIM * F_DIM;

  int srow[4], scoff[4];
  #pragma unroll
  for (int i = 0; i < 4; i++) {
    int id = i * 256 + tid;
    srow[i] = ((id >> 7) << 4) | (id & 15);
    scoff[i] = ((id >> 4) & 7) * 8;
  }

  f32x4 acc[4][4];
  #pragma unroll
  for (int m = 0; m < 4; m++)
    #pragma unroll
    for (int n = 0; n < 4; n++) acc[m][n] = (f32x4)(0.f);

  for (int f0 = 0; f0 < F_DIM; f0 += 64) {
    #pragma unroll
    for (int i = 0; i < 4; i++) {
      int id = i * 256 + tid;
      gload_lds16(H     + (size_t)(row0 + srow[i]) * F_DIM + f0 + scoff[i], &As[id * 8]);
      gload_lds16(Bbase + (size_t)(bn * 128 + srow[i]) * F_DIM + f0 + scoff[i], &Bs[id * 8]);
    }
    __syncthreads();
    #pragma unroll
    for (int kk = 0; kk < 64; kk += 32) {
      bf16x8 af[4], bfr[4];
      #pragma unroll
      for (int m = 0; m < 4; m++)
        af[m] = *(const bf16x8*)&As[(wm * 4 + m) * 1024 + kk * 16 + lane * 8];
      #pragma unroll
      for (int n = 0; n < 4; n++)
        bfr[n] = *(const bf16x8*)&Bs[(wn * 4 + n) * 1024 + kk * 16 + lane * 8];
      #pragma unroll
      for (int m = 0; m < 4; m++)
        #pragma unroll
        for (int n = 0; n < 4; n++)
          acc[m][n] = __builtin_amdgcn_mfma_f32_16x16x32_bf16(af[m], bfr[n], acc[m][n], 0, 0, 0);
    }
    __syncthreads();
  }

  #pragma unroll
  for (int m = 0; m < 4; m++) {
    #pragma unroll
    for (int r = 0; r < 4; r++) {
      int rl = wm * 64 + m * 16 + (lane >> 4) * 4 + r;
      #pragma unroll
      for (int n = 0; n < 4; n++) {
        int col = bn * 128 + wn * 64 + n * 16 + (lane & 15);
        Yr[(size_t)(row0 + rl) * D_DIM + col] = f2bf(acc[m][n][r]);
      }
    }
  }
}

// ---------------- GEMM2 shared: out[t] = [Hsh0|Hsh1][t] @ [W2sh0;W2sh1] + biases
// token-major, K=1024. One writer per out element (no atomics).
__global__ __launch_bounds__(256) void k_gemm2s(
    const short* __restrict__ H, const short* __restrict__ w2t,
    const int2* __restrict__ ti, const float2* __restrict__ tg,
    const float* __restrict__ eb2, const float* __restrict__ sb2,
    float* __restrict__ out) {
  const int bm = blockIdx.x, bn = blockIdx.y;
  __shared__ __align__(16) short As[128 * 64];
  __shared__ __align__(16) short Bs[128 * 64];
  const int tid = threadIdx.x;
  const int lane = tid & 63;
  const int wv = tid >> 6;
  const int wm = wv >> 1, wn = wv & 1;

  int srow[4], scoff[4];
  #pragma unroll
  for (int i = 0; i < 4; i++) {
    int id = i * 256 + tid;
    srow[i] = ((id >> 7) << 4) | (id & 15);
    scoff[i] = ((id >> 4) & 7) * 8;
  }

  f32x4 acc[4][4];
  #pragma unroll
  for (int m = 0; m < 4; m++)
    #pragma unroll
    for (int n = 0; n < 4; n++) acc[m][n] = (f32x4)(0.f);

  for (int k0 = 0; k0 < 2 * F_DIM; k0 += 64) {
    const int half = k0 >> 9;                 // 0 or 1
    const int f0 = k0 & 511;
    const short* Ab = H + (size_t)(SH_BASE + half * TOKENS) * F_DIM;
    const short* Bb = w2t + (size_t)(NE + half) * D_DIM * F_DIM;
    #pragma unroll
    for (int i = 0; i < 4; i++) {
      int id = i * 256 + tid;
      gload_lds16(Ab + (size_t)(bm * 128 + srow[i]) * F_DIM + f0 + scoff[i], &As[id * 8]);
      gload_lds16(Bb + (size_t)(bn * 128 + srow[i]) * F_DIM + f0 + scoff[i], &Bs[id * 8]);
    }
    __syncthreads();
    #pragma unroll
    for (int kk = 0; kk < 64; kk += 32) {
      bf16x8 af[4], bfr[4];
      #pragma unroll
      for (int m = 0; m < 4; m++)
        af[m] = *(const bf16x8*)&As[(wm * 4 + m) * 1024 + kk * 16 + lane * 8];
      #pragma unroll
      for (int n = 0; n < 4; n++)
        bfr[n] = *(const bf16x8*)&Bs[(wn * 4 + n) * 1024 + kk * 16 + lane * 8];
      #pragma unroll
      for (int m = 0; m < 4; m++)
        #pragma unroll
        for (int n = 0; n < 4; n++)
          acc[m][n] = __builtin_amdgcn_mfma_f32_16x16x32_bf16(af[m], bfr[n], acc[m][n], 0, 0, 0);
    }
    __syncthreads();
  }

  #pragma unroll
  for (int m = 0; m < 4; m++) {
    #pragma unroll
    for (int r = 0; r < 4; r++) {
      int row = bm * 128 + wm * 64 + m * 16 + (lane >> 4) * 4 + r;
      int2 ii = ti[row]; float2 gg = tg[row];
      #pragma unroll
      for (int n = 0; n < 4; n++) {
        int col = bn * 128 + wn * 64 + n * 16 + (lane & 15);
        float v = acc[m][n][r]
                + gg.x * eb2[(size_t)ii.x * D_DIM + col]
                + gg.y * eb2[(size_t)ii.y * D_DIM + col]
                + sb2[col] + sb2[D_DIM + col];
        out[(size_t)row * D_DIM + col] = v;
      }
    }
  }
}

// ---------------- combine: out[t] += Yr[pos0] + Yr[pos1] --------------------
__global__ __launch_bounds__(256) void k_combine(
    const short* __restrict__ Yr, const int2* __restrict__ pos,
    float* __restrict__ out) {
  int idx = blockIdx.x * 256 + threadIdx.x;   // over TOKENS*D_DIM/8
  int t = idx >> 8;
  int c = (idx & 255) * 8;
  int2 p = pos[t];
  bf16x8 a = *(const bf16x8*)&Yr[(size_t)p.x * D_DIM + c];
  bf16x8 b = *(const bf16x8*)&Yr[(size_t)p.y * D_DIM + c];
  float4 o0 = *(float4*)&out[(size_t)t * D_DIM + c];
  float4 o1 = *(float4*)&out[(size_t)t * D_DIM + c + 4];
  o0.x += bf2f(a[0]) + bf2f(b[0]);
  o0.y += bf2f(a[1]) + bf2f(b[1]);
  o0.z += bf2f(a[2]) + bf2f(b[2]);
  o0.w += bf2f(a[3]) + bf2f(b[3]);
  o1.x += bf2f(a[4]) + bf2f(b[4]);
  o1.y += bf2f(a[5]) + bf2f(b[5]);
  o1.z += bf2f(a[6]) + bf2f(b[6]);
  o1.w += bf2f(a[7]) + bf2f(b[7]);
  *(float4*)&out[(size_t)t * D_DIM + c] = o0;
  *(float4*)&out[(size_t)t * D_DIM + c + 4] = o1;
}

// ---------------------------------------------------------------------------
extern "C" void kernel_launch(void* const* d_in, const int* in_sizes, int n_in,
                              void* d_out, int out_size, void* d_ws, size_t ws_size,
                              hipStream_t stream) {
  (void)in_sizes; (void)n_in; (void)out_size; (void)ws_size;
  const float* x        = (const float*)d_in[0];
  const float* router_w = (const float*)d_in[1];
  const float* router_b = (const float*)d_in[2];
  const float* ew1      = (const float*)d_in[3];
  const float* eb1      = (const float*)d_in[4];
  const float* ew2      = (const float*)d_in[5];
  const float* eb2      = (const float*)d_in[6];
  const float* sw1      = (const float*)d_in[7];
  const float* sb1      = (const float*)d_in[8];
  const float* sw2      = (const float*)d_in[9];
  const float* sb2      = (const float*)d_in[10];
  float* out = (float*)d_out;

  // workspace layout (Yr aliases xb+w1t, which are dead after k_gemm1):
  //   w2t   : 20,971,520 B
  //   Hbuf  : 34,603,008 B
  //   small : ti/tg/pos/pair/meta/tiles ~ 600 KB
  //   xb    : 33,554,432 B  <-+-- Yr = RCAP*2048*2 = 71,303,168 B overlays here
  //   w1t   : 20,971,520 B  <-+   (needs 16.8 MB past w1t end)
  //   total ≈ 128 MB
  char* ws = (char*)d_ws;
  short*  w2t       = (short*)ws;
  short*  Hbuf      = w2t + (size_t)NZ * D_DIM * F_DIM;
  int2*   ti        = (int2*)(Hbuf + (size_t)NPAIRS * F_DIM);
  float2* tg        = (float2*)(ti + TOKENS);
  int2*   pos       = (int2*)(tg + TOKENS);
  int*    pair_tok  = (int*)(pos + TOKENS);
  float*  pair_gate = (float*)(pair_tok + NPAIRS);
  int*    meta      = (int*)(pair_gate + NPAIRS);
  int*    tile_z    = meta + 32;
  int*    tile_row  = tile_z + NTILES;
  short*  xb        = (short*)(((uintptr_t)(tile_row + NTILES) + 255) & ~(uintptr_t)255);
  short*  w1t       = xb + (size_t)TOKENS * D_DIM;
  short*  Yr        = xb;   // alias (valid after k_gemm1 completes)

  k_convert<<<2048, 256, 0, stream>>>(x, xb, TOKENS * D_DIM / 4);
  k_transpose<<<dim3(F_DIM / 32, D_DIM / 32, NE),  dim3(32, 8), 0, stream>>>(ew1, w1t, D_DIM, F_DIM);
  k_transpose<<<dim3(F_DIM / 32, D_DIM / 32, NSH), dim3(32, 8), 0, stream>>>(sw1, w1t + (size_t)NE * F_DIM * D_DIM, D_DIM, F_DIM);
  k_transpose<<<dim3(D_DIM / 32, F_DIM / 32, NE),  dim3(32, 8), 0, stream>>>(ew2, w2t, F_DIM, D_DIM);
  k_transpose<<<dim3(D_DIM / 32, F_DIM / 32, NSH), dim3(32, 8), 0, stream>>>(sw2, w2t + (size_t)NE * D_DIM * F_DIM, F_DIM, D_DIM);

  k_init<<<(RCAP + 255) / 256, 256, 0, stream>>>(pair_tok, pair_gate);
  k_router<<<TOKENS / 4, 256, 0, stream>>>(x, router_w, router_b, ti, tg);
  k_count<<<1, 1024, 0, stream>>>(ti, meta, tile_z, tile_row);
  k_assign<<<TOKENS / 256, 256, 0, stream>>>(ti, tg, meta, pair_tok, pair_gate, pos);
  k_loss<<<1, 64, 0, stream>>>(meta, out + OUT_ELEMS);

  k_gemm1<<<dim3(NTILES, F_DIM / 128), 256, 0, stream>>>(
      xb, w1t, eb1, sb1, meta, tile_z, tile_row, pair_tok, pair_gate, Hbuf);
  k_gemm2r<<<dim3(MAX_RT, D_DIM / 128), 256, 0, stream>>>(
      Hbuf, w2t, meta, tile_z, tile_row, Yr);
  k_gemm2s<<<dim3(TOKENS / 128, D_DIM / 128), 256, 0, stream>>>(
      Hbuf, w2t, ti, tg, eb2, sb2, out);
  k_combine<<<OUT_ELEMS / 8 / 256, 256, 0, stream>>>(Yr, pos, out);
}

// Round 5
// 504.128 us; speedup vs baseline: 1.7433x; 1.1260x over previous
//
#include <hip/hip_runtime.h>
#include <hip/hip_bf16.h>
#include <cstdint>

// Problem constants (B=2,S=4096,D=2048,E=8,SH=2,F=512,K=2)
#define TOKENS   8192
#define D_DIM    2048
#define F_DIM    512
#define NE       8
#define NSH      2
#define NZ       10
#define OUT_ELEMS (TOKENS * D_DIM)

// pair bookkeeping: routed capacity padded to 256-row tiles, then shared pairs
#define RCAP256   18432                 // sum ceil(c_e/256)*256 <= 16384+8*255 -> 18432
#define SH_B256   RCAP256
#define NPAIRS256 (RCAP256 + 2 * TOKENS)  // 34816
#define MAX_RT256 72                    // max routed 256-row M-tiles
#define G1_SLOTS  136                   // 72 routed + 64 shared (GEMM1)
#define G2_SLOTS  104                   // 72 routed + 32 shared-token (GEMM2)

typedef __attribute__((ext_vector_type(8))) short bf16x8;
typedef __attribute__((ext_vector_type(4))) float f32x4;

__device__ __forceinline__ short f2bf(float f) {
  union { float f; uint32_t u; } v; v.f = f;
  uint32_t r = (v.u + 0x7fffu + ((v.u >> 16) & 1u)) >> 16;
  return (short)r;
}
__device__ __forceinline__ float bf2f(short s) {
  union { float f; uint32_t u; } v; v.u = ((uint32_t)(uint16_t)s) << 16; return v.f;
}

__device__ __forceinline__ void gload_lds16(const void* g, void* l) {
  __builtin_amdgcn_global_load_lds(
      (const __attribute__((address_space(1))) unsigned int*)g,
      (__attribute__((address_space(3))) unsigned int*)l,
      16, 0, 0);
}

// ---------------- convert fp32 -> bf16 -------------------------------------
__global__ void k_convert(const float* __restrict__ in, short* __restrict__ out, int n4) {
  int i = blockIdx.x * blockDim.x + threadIdx.x;
  int stride = gridDim.x * blockDim.x;
  for (; i < n4; i += stride) {
    float4 v = ((const float4*)in)[i];
    short4 o;
    o.x = f2bf(v.x); o.y = f2bf(v.y); o.z = f2bf(v.z); o.w = f2bf(v.w);
    ((short4*)out)[i] = o;
  }
}

// ------------- transpose-convert fp32 (R,C) -> bf16 (C,R), batched ----------
__global__ void k_transpose(const float* __restrict__ in, short* __restrict__ out,
                            int R, int C) {
  __shared__ float tile[32][33];
  int b = blockIdx.z;
  in  += (size_t)b * R * C;
  out += (size_t)b * R * C;
  int c0 = blockIdx.x * 32, r0 = blockIdx.y * 32;
  #pragma unroll
  for (int i = 0; i < 32; i += 8) {
    int r = r0 + threadIdx.y + i, c = c0 + threadIdx.x;
    tile[threadIdx.y + i][threadIdx.x] = in[(size_t)r * C + c];
  }
  __syncthreads();
  #pragma unroll
  for (int i = 0; i < 32; i += 8) {
    int c = c0 + threadIdx.y + i, r = r0 + threadIdx.x;
    out[(size_t)c * R + r] = f2bf(tile[threadIdx.x][threadIdx.y + i]);
  }
}

// ---------------- zero pad region of pair arrays ----------------------------
__global__ void k_init(int* __restrict__ pair_tok, float* __restrict__ pair_gate) {
  int i = blockIdx.x * blockDim.x + threadIdx.x;
  if (i < RCAP256) { pair_tok[i] = 0; pair_gate[i] = 0.f; }
}

// ---------------- router: wave-per-token, fp32, exact top-2 -----------------
__global__ __launch_bounds__(256) void k_router(
    const float* __restrict__ x, const float* __restrict__ rw,
    const float* __restrict__ rb, int2* __restrict__ ti, float2* __restrict__ tg) {
  int wave = threadIdx.x >> 6;
  int lane = threadIdx.x & 63;
  int t = blockIdx.x * 4 + wave;
  const float* xr = x + (size_t)t * D_DIM;
  float acc[NE];
  #pragma unroll
  for (int e = 0; e < NE; e++) acc[e] = 0.f;
  for (int d = lane; d < D_DIM; d += 64) {
    float xv = xr[d];
    #pragma unroll
    for (int e = 0; e < NE; e++) acc[e] += xv * rw[e * D_DIM + d];
  }
  #pragma unroll
  for (int e = 0; e < NE; e++) {
    #pragma unroll
    for (int off = 32; off > 0; off >>= 1) acc[e] += __shfl_xor(acc[e], off);
  }
  if (lane == 0) {
    float lg[NE];
    #pragma unroll
    for (int e = 0; e < NE; e++) lg[e] = acc[e] + rb[e];
    int i0 = 0;
    #pragma unroll
    for (int e = 1; e < NE; e++) if (lg[e] > lg[i0]) i0 = e;
    int i1 = (i0 == 0) ? 1 : 0;
    #pragma unroll
    for (int e = 0; e < NE; e++) if (e != i0 && e != i1 && lg[e] > lg[i1]) i1 = e;
    float e1 = __expf(lg[i1] - lg[i0]);
    float inv = 1.f / (1.f + e1);
    ti[t] = make_int2(i0, i1);
    tg[t] = make_float2(inv, e1 * inv);
  }
}

// ------------- count + segment bases + tile table (single block) ------------
// meta: [0..7]=counts [8..15]=cursor [16..17]=loss counts [18]=n_routed_tiles
//       [19..26]=seg_base
__global__ __launch_bounds__(1024) void k_count(
    const int2* __restrict__ ti, int* __restrict__ meta,
    int* __restrict__ tile_z, int* __restrict__ tile_row) {
  __shared__ int cnt[NE + 2];
  if (threadIdx.x < NE + 2) cnt[threadIdx.x] = 0;
  __syncthreads();
  int loc[NE]; int l0 = 0, l1 = 0;
  #pragma unroll
  for (int e = 0; e < NE; e++) loc[e] = 0;
  for (int t = threadIdx.x; t < TOKENS; t += 1024) {
    int2 ii = ti[t];
    loc[ii.x]++; loc[ii.y]++;
    l0 += (ii.x == 0); l1 += (ii.y == 1);
  }
  #pragma unroll
  for (int e = 0; e < NE; e++) if (loc[e]) atomicAdd(&cnt[e], loc[e]);
  if (l0) atomicAdd(&cnt[NE], l0);
  if (l1) atomicAdd(&cnt[NE + 1], l1);
  __syncthreads();
  if (threadIdx.x == 0) {
    int base = 0, nrt = 0;
    #pragma unroll
    for (int e = 0; e < NE; e++) {
      int c = cnt[e];
      meta[e] = c;
      meta[19 + e] = base;
      meta[8 + e] = 0;                       // cursor
      int nt = (c + 255) >> 8;
      for (int i = 0; i < nt; i++) { tile_z[nrt] = e; tile_row[nrt] = base + i * 256; nrt++; }
      base += nt * 256;
    }
    meta[16] = cnt[NE]; meta[17] = cnt[NE + 1];
    meta[18] = nrt;
    for (int i = 0; i < 64; i++) {           // shared tiles for GEMM1
      tile_z[MAX_RT256 + i] = NE + (i >> 5);
      tile_row[MAX_RT256 + i] = SH_B256 + (i >> 5) * TOKENS + (i & 31) * 256;
    }
  }
}

// ---------------- assignment: ballot-scan within wave + inverse map ---------
__global__ __launch_bounds__(256) void k_assign(
    const int2* __restrict__ ti, const float2* __restrict__ tg,
    int* __restrict__ meta, int* __restrict__ pair_tok, float* __restrict__ pair_gate,
    int2* __restrict__ pos) {
  int t = blockIdx.x * 256 + threadIdx.x;
  int lane = threadIdx.x & 63;
  int2 ii = ti[t];
  float2 gg = tg[t];
  int2 mypos;
  unsigned long long below = (1ull << lane) - 1ull;
  #pragma unroll
  for (int e = 0; e < NE; e++) {
    unsigned long long m0 = __ballot(ii.x == e);
    unsigned long long m1 = __ballot(ii.y == e);
    unsigned c = __popcll(m0) + __popcll(m1);
    unsigned base = 0;
    if (lane == 0 && c) base = atomicAdd((unsigned*)&meta[8 + e], c);
    base = __shfl((int)base, 0);
    int seg = meta[19 + e];
    if (ii.x == e) {
      int p = seg + base + __popcll(m0 & below);
      pair_tok[p] = t; pair_gate[p] = gg.x; mypos.x = p;
    }
    if (ii.y == e) {
      int p = seg + base + __popcll(m0) + __popcll(m1 & below);
      pair_tok[p] = t; pair_gate[p] = gg.y; mypos.y = p;
    }
  }
  pos[t] = mypos;
  pair_tok[SH_B256 + t] = t;            pair_gate[SH_B256 + t] = 1.f;
  pair_tok[SH_B256 + TOKENS + t] = t;   pair_gate[SH_B256 + TOKENS + t] = 1.f;
}

// ---------------- aux loss --------------------------------------------------
__global__ void k_loss(const int* __restrict__ meta, float* __restrict__ out_loss) {
  if (threadIdx.x == 0 && blockIdx.x == 0) {
    float p0 = (float)meta[16] / 16384.0f + 1e-8f;
    float p1 = (float)meta[17] / 16384.0f + 1e-8f;
    float rest = 6.0f * (1e-8f * logf(1e-8f));
    out_loss[0] = -(p0 * logf(p0) + p1 * logf(p1) + rest);
  }
}

// ============================================================================
// 256x256-tile, 8-wave, 4-phase/K-tile GEMM core with counted vmcnt.
// LDS per buffer per matrix: half h at [h*8192, +8192): chunk(row,c8) at
//   (row>>4)*1024 + c8*128 + (row&15)*8 ; staged linearly per wave wv.
// Phase p (quadrant MH,NH):
//   [vmcnt(4) for p<3] -> s_barrier -> fence -> ds_read(cur) -> STAGE(nb)
//   -> lgkmcnt(0) -> sched_barrier -> setprio(1) 16xMFMA setprio(0)
// Cross-wave safety: data read in phase p was drained (per-wave vmcnt FIFO:
// PH00 completes A_t h0+B_t h0, PH01 -> B_t h1, PH10 -> A_t h1) by ALL waves
// before the barrier that precedes p's reads. Stage targets buffer nb only;
// WAR separated by >=3 barriers. vmcnt never 0 inside the loop.
// ============================================================================
#define PH(MH, NH, DO_WAIT, STAGE_STMT) do {                                  \
    if (DO_WAIT) asm volatile("s_waitcnt vmcnt(4)" ::: "memory");             \
    __builtin_amdgcn_s_barrier();                                             \
    asm volatile("" ::: "memory");                                            \
    bf16x8 afr[4][2], bfr[2][2];                                              \
    const short* Ab_ = &As[cur][0]; const short* Bb_ = &Bs[cur][0];           \
    _Pragma("unroll") for (int m_ = 0; m_ < 4; m_++)                          \
      _Pragma("unroll") for (int kk = 0; kk < 2; kk++)                        \
        afr[m_][kk] = *(const bf16x8*)&Ab_[((MH)*8 + wm*4 + m_)*1024 + kk*512 + lane*8]; \
    _Pragma("unroll") for (int n_ = 0; n_ < 2; n_++)                          \
      _Pragma("unroll") for (int kk = 0; kk < 2; kk++)                        \
        bfr[n_][kk] = *(const bf16x8*)&Bb_[((NH)*8 + wn*2 + n_)*1024 + kk*512 + lane*8]; \
    STAGE_STMT;                                                               \
    asm volatile("s_waitcnt lgkmcnt(0)" ::: "memory");                        \
    __builtin_amdgcn_sched_barrier(0);                                        \
    __builtin_amdgcn_s_setprio(1);                                            \
    _Pragma("unroll") for (int m_ = 0; m_ < 4; m_++)                          \
      _Pragma("unroll") for (int n_ = 0; n_ < 2; n_++)                        \
        _Pragma("unroll") for (int kk = 0; kk < 2; kk++)                      \
          acc[(MH)*4+m_][(NH)*2+n_] = __builtin_amdgcn_mfma_f32_16x16x32_bf16( \
              afr[m_][kk], bfr[n_][kk], acc[(MH)*4+m_][(NH)*2+n_], 0, 0, 0);  \
    __builtin_amdgcn_s_setprio(0);                                            \
  } while (0)

// ---------------- GEMM1: H[p] = gelu(x[tok(p)]@W1[z]+b1)*gate ---------------
// grid (2, 136): x=bn (256-col tile of F=512), y=slot. block 512.
__global__ __launch_bounds__(512, 2) void k_gemm1(
    const short* __restrict__ xb, const short* __restrict__ w1t,
    const float* __restrict__ eb1, const float* __restrict__ sb1,
    const int* __restrict__ meta, const int* __restrict__ tile_z,
    const int* __restrict__ tile_row, const int* __restrict__ pair_tok,
    const float* __restrict__ pair_gate, short* __restrict__ H) {
  const int slot = blockIdx.y;
  if (slot < MAX_RT256 && slot >= meta[18]) return;
  const int z = tile_z[slot];
  const int row0 = tile_row[slot];
  const int bn = blockIdx.x;
  __shared__ __align__(16) short As[2][16384];
  __shared__ __align__(16) short Bs[2][16384];
  const int tid = threadIdx.x;
  const int lane = tid & 63;
  const int wv = tid >> 6;          // 0..7
  const int wm = wv >> 2;           // 0..1
  const int wn = wv & 3;            // 0..3

  const int srlow = (wv << 4) | (lane & 15);
  const int scol0 = (lane >> 4) * 8;
  const short* aptr[2]; const short* bptr[2];
  {
    int tA0 = pair_tok[row0 + srlow];
    int tA1 = pair_tok[row0 + 128 + srlow];
    aptr[0] = xb + (size_t)tA0 * D_DIM + scol0;
    aptr[1] = xb + (size_t)tA1 * D_DIM + scol0;
    const short* wb = w1t + (size_t)z * F_DIM * D_DIM;
    bptr[0] = wb + (size_t)(bn * 256 + srlow) * D_DIM + scol0;
    bptr[1] = wb + (size_t)(bn * 256 + 128 + srlow) * D_DIM + scol0;
  }

  f32x4 acc[8][4];
  #pragma unroll
  for (int m = 0; m < 8; m++)
    #pragma unroll
    for (int n = 0; n < 4; n++) acc[m][n] = (f32x4)(0.f);

  #define ST_A(B, HH, K0) do {                                        \
      gload_lds16(aptr[HH] + (K0),      &As[B][(HH)*8192 + wv*1024]);  \
      gload_lds16(aptr[HH] + (K0) + 32, &As[B][(HH)*8192 + wv*1024 + 512]); } while (0)
  #define ST_B(B, HH, K0) do {                                        \
      gload_lds16(bptr[HH] + (K0),      &Bs[B][(HH)*8192 + wv*1024]);  \
      gload_lds16(bptr[HH] + (K0) + 32, &Bs[B][(HH)*8192 + wv*1024 + 512]); } while (0)

  // prologue: tile 0 -> buf 0, order Ah0,Bh0,Bh1,Ah1
  ST_A(0, 0, 0); ST_B(0, 0, 0); ST_B(0, 1, 0); ST_A(0, 1, 0);

  const int NT = D_DIM / 64;   // 32
  for (int t = 0; t < NT; ++t) {
    const int cur = t & 1, nb = cur ^ 1;
    const int kn = ((t + 1 < NT) ? (t + 1) : t) * 64;
    PH(0, 0, 1, ST_A(nb, 0, kn));
    PH(0, 1, 1, ST_B(nb, 0, kn));
    PH(1, 0, 1, ST_B(nb, 1, kn));
    PH(1, 1, 0, ST_A(nb, 1, kn));
  }
  #undef ST_A
  #undef ST_B
  asm volatile("s_waitcnt vmcnt(0)" ::: "memory");

  const float* b1 = (z < NE) ? (eb1 + z * F_DIM) : (sb1 + (size_t)(z - NE) * F_DIM);
  #pragma unroll
  for (int m = 0; m < 8; m++) {
    const int mh = m >> 2, m_ = m & 3;
    #pragma unroll
    for (int r = 0; r < 4; r++) {
      int row = mh * 128 + wm * 64 + m_ * 16 + (lane >> 4) * 4 + r;
      float g = pair_gate[row0 + row];
      #pragma unroll
      for (int n = 0; n < 4; n++) {
        const int nh = n >> 1, n_ = n & 1;
        int col = bn * 256 + nh * 128 + wn * 32 + n_ * 16 + (lane & 15);
        float c = acc[m][n][r] + b1[col];
        float h = 0.5f * c * (1.0f + erff(c * 0.70710678118654752440f));
        H[(size_t)(row0 + row) * F_DIM + col] = f2bf(h * g);
      }
    }
  }
}

// ---------------- GEMM2 unified: routed->Yr (K=512), shared->out (K=1024) ---
// grid (8, 104): x=bn (256-col tile of D=2048), y=slot. block 512.
__global__ __launch_bounds__(512, 2) void k_gemm2(
    const short* __restrict__ Hb, const short* __restrict__ w2t,
    const int* __restrict__ meta, const int* __restrict__ tile_z,
    const int* __restrict__ tile_row,
    const int2* __restrict__ ti, const float2* __restrict__ tg,
    const float* __restrict__ eb2, const float* __restrict__ sb2,
    short* __restrict__ Yr, float* __restrict__ out) {
  const int slot = blockIdx.y;
  const bool shared = (slot >= MAX_RT256);
  if (!shared && slot >= meta[18]) return;
  const int z = shared ? 0 : tile_z[slot];
  const int row0 = shared ? 0 : tile_row[slot];
  const int t0 = shared ? (slot - MAX_RT256) * 256 : 0;
  const int bn = blockIdx.x;
  __shared__ __align__(16) short As[2][16384];
  __shared__ __align__(16) short Bs[2][16384];
  const int tid = threadIdx.x;
  const int lane = tid & 63;
  const int wv = tid >> 6;
  const int wm = wv >> 2;
  const int wn = wv & 3;

  const int srlow = (wv << 4) | (lane & 15);
  const int scol0 = (lane >> 4) * 8;

  f32x4 acc[8][4];
  #pragma unroll
  for (int m = 0; m < 8; m++)
    #pragma unroll
    for (int n = 0; n < 4; n++) acc[m][n] = (f32x4)(0.f);

  auto stA = [&](int b, int h, int k0) {
    const short* p;
    if (shared) {
      p = Hb + (size_t)(SH_B256 + ((k0 >= F_DIM) ? TOKENS : 0) + t0 + h * 128 + srlow) * F_DIM
            + (k0 & (F_DIM - 1)) + scol0;
    } else {
      p = Hb + (size_t)(row0 + h * 128 + srlow) * F_DIM + k0 + scol0;
    }
    gload_lds16(p,      &As[b][h * 8192 + wv * 1024]);
    gload_lds16(p + 32, &As[b][h * 8192 + wv * 1024 + 512]);
  };
  auto stB = [&](int b, int h, int k0) {
    const short* p;
    if (shared) {
      p = w2t + (size_t)(NE + ((k0 >= F_DIM) ? 1 : 0)) * D_DIM * F_DIM
              + (size_t)(bn * 256 + h * 128 + srlow) * F_DIM + (k0 & (F_DIM - 1)) + scol0;
    } else {
      p = w2t + (size_t)z * D_DIM * F_DIM
              + (size_t)(bn * 256 + h * 128 + srlow) * F_DIM + k0 + scol0;
    }
    gload_lds16(p,      &Bs[b][h * 8192 + wv * 1024]);
    gload_lds16(p + 32, &Bs[b][h * 8192 + wv * 1024 + 512]);
  };

  // prologue
  stA(0, 0, 0); stB(0, 0, 0); stB(0, 1, 0); stA(0, 1, 0);

  const int NT = shared ? (2 * F_DIM / 64) : (F_DIM / 64);   // 16 or 8
  for (int t = 0; t < NT; ++t) {
    const int cur = t & 1, nb = cur ^ 1;
    const int kn = ((t + 1 < NT) ? (t + 1) : t) * 64;
    PH(0, 0, 1, stA(nb, 0, kn));
    PH(0, 1, 1, stB(nb, 0, kn));
    PH(1, 0, 1, stB(nb, 1, kn));
    PH(1, 1, 0, stA(nb, 1, kn));
  }
  asm volatile("s_waitcnt vmcnt(0)" ::: "memory");

  if (!shared) {
    #pragma unroll
    for (int m = 0; m < 8; m++) {
      const int mh = m >> 2, m_ = m & 3;
      #pragma unroll
      for (int r = 0; r < 4; r++) {
        int row = mh * 128 + wm * 64 + m_ * 16 + (lane >> 4) * 4 + r;
        #pragma unroll
        for (int n = 0; n < 4; n++) {
          const int nh = n >> 1, n_ = n & 1;
          int col = bn * 256 + nh * 128 + wn * 32 + n_ * 16 + (lane & 15);
          Yr[(size_t)(row0 + row) * D_DIM + col] = f2bf(acc[m][n][r]);
        }
      }
    }
  } else {
    #pragma unroll
    for (int m = 0; m < 8; m++) {
      const int mh = m >> 2, m_ = m & 3;
      #pragma unroll
      for (int r = 0; r < 4; r++) {
        int row = t0 + mh * 128 + wm * 64 + m_ * 16 + (lane >> 4) * 4 + r;
        int2 ii = ti[row]; float2 gg = tg[row];
        #pragma unroll
        for (int n = 0; n < 4; n++) {
          const int nh = n >> 1, n_ = n & 1;
          int col = bn * 256 + nh * 128 + wn * 32 + n_ * 16 + (lane & 15);
          float v = acc[m][n][r]
                  + gg.x * eb2[(size_t)ii.x * D_DIM + col]
                  + gg.y * eb2[(size_t)ii.y * D_DIM + col]
                  + sb2[col] + sb2[D_DIM + col];
          out[(size_t)row * D_DIM + col] = v;
        }
      }
    }
  }
}

// ---------------- combine: out[t] += Yr[pos0] + Yr[pos1] --------------------
__global__ __launch_bounds__(256) void k_combine(
    const short* __restrict__ Yr, const int2* __restrict__ pos,
    float* __restrict__ out) {
  int idx = blockIdx.x * 256 + threadIdx.x;   // over TOKENS*D_DIM/8
  int t = idx >> 8;
  int c = (idx & 255) * 8;
  int2 p = pos[t];
  bf16x8 a = *(const bf16x8*)&Yr[(size_t)p.x * D_DIM + c];
  bf16x8 b = *(const bf16x8*)&Yr[(size_t)p.y * D_DIM + c];
  float4 o0 = *(float4*)&out[(size_t)t * D_DIM + c];
  float4 o1 = *(float4*)&out[(size_t)t * D_DIM + c + 4];
  o0.x += bf2f(a[0]) + bf2f(b[0]);
  o0.y += bf2f(a[1]) + bf2f(b[1]);
  o0.z += bf2f(a[2]) + bf2f(b[2]);
  o0.w += bf2f(a[3]) + bf2f(b[3]);
  o1.x += bf2f(a[4]) + bf2f(b[4]);
  o1.y += bf2f(a[5]) + bf2f(b[5]);
  o1.z += bf2f(a[6]) + bf2f(b[6]);
  o1.w += bf2f(a[7]) + bf2f(b[7]);
  *(float4*)&out[(size_t)t * D_DIM + c] = o0;
  *(float4*)&out[(size_t)t * D_DIM + c + 4] = o1;
}

// ---------------------------------------------------------------------------
extern "C" void kernel_launch(void* const* d_in, const int* in_sizes, int n_in,
                              void* d_out, int out_size, void* d_ws, size_t ws_size,
                              hipStream_t stream) {
  (void)in_sizes; (void)n_in; (void)out_size; (void)ws_size;
  const float* x        = (const float*)d_in[0];
  const float* router_w = (const float*)d_in[1];
  const float* router_b = (const float*)d_in[2];
  const float* ew1      = (const float*)d_in[3];
  const float* eb1      = (const float*)d_in[4];
  const float* ew2      = (const float*)d_in[5];
  const float* eb2      = (const float*)d_in[6];
  const float* sw1      = (const float*)d_in[7];
  const float* sb1      = (const float*)d_in[8];
  const float* sw2      = (const float*)d_in[9];
  const float* sb2      = (const float*)d_in[10];
  float* out = (float*)d_out;

  // workspace layout (Yr aliases xb+w1t+overhang; dead after k_gemm1):
  //   w2t 20.97MB | Hbuf 35.65MB | small ~0.6MB | xb 33.55MB | w1t 20.97MB |
  //   Yr-overhang ~21MB  => total ~132.7MB
  char* ws = (char*)d_ws;
  short*  w2t       = (short*)ws;
  short*  Hbuf      = w2t + (size_t)NZ * D_DIM * F_DIM;
  int2*   ti        = (int2*)(Hbuf + (size_t)NPAIRS256 * F_DIM);
  float2* tg        = (float2*)(ti + TOKENS);
  int2*   pos       = (int2*)(tg + TOKENS);
  int*    pair_tok  = (int*)(pos + TOKENS);
  float*  pair_gate = (float*)(pair_tok + NPAIRS256);
  int*    meta      = (int*)(pair_gate + NPAIRS256);
  int*    tile_z    = meta + 32;
  int*    tile_row  = tile_z + 256;
  short*  xb        = (short*)(((uintptr_t)(tile_row + 256) + 255) & ~(uintptr_t)255);
  short*  w1t       = xb + (size_t)TOKENS * D_DIM;
  short*  Yr        = xb;   // alias (valid after k_gemm1 completes)

  k_convert<<<2048, 256, 0, stream>>>(x, xb, TOKENS * D_DIM / 4);
  k_transpose<<<dim3(F_DIM / 32, D_DIM / 32, NE),  dim3(32, 8), 0, stream>>>(ew1, w1t, D_DIM, F_DIM);
  k_transpose<<<dim3(F_DIM / 32, D_DIM / 32, NSH), dim3(32, 8), 0, stream>>>(sw1, w1t + (size_t)NE * F_DIM * D_DIM, D_DIM, F_DIM);
  k_transpose<<<dim3(D_DIM / 32, F_DIM / 32, NE),  dim3(32, 8), 0, stream>>>(ew2, w2t, F_DIM, D_DIM);
  k_transpose<<<dim3(D_DIM / 32, F_DIM / 32, NSH), dim3(32, 8), 0, stream>>>(sw2, w2t + (size_t)NE * D_DIM * F_DIM, F_DIM, D_DIM);

  k_init<<<(RCAP256 + 255) / 256, 256, 0, stream>>>(pair_tok, pair_gate);
  k_router<<<TOKENS / 4, 256, 0, stream>>>(x, router_w, router_b, ti, tg);
  k_count<<<1, 1024, 0, stream>>>(ti, meta, tile_z, tile_row);
  k_assign<<<TOKENS / 256, 256, 0, stream>>>(ti, tg, meta, pair_tok, pair_gate, pos);
  k_loss<<<1, 64, 0, stream>>>(meta, out + OUT_ELEMS);

  k_gemm1<<<dim3(2, G1_SLOTS), 512, 0, stream>>>(
      xb, w1t, eb1, sb1, meta, tile_z, tile_row, pair_tok, pair_gate, Hbuf);
  k_gemm2<<<dim3(8, G2_SLOTS), 512, 0, stream>>>(
      Hbuf, w2t, meta, tile_z, tile_row, ti, tg, eb2, sb2, Yr, out);
  k_combine<<<OUT_ELEMS / 8 / 256, 256, 0, stream>>>(Yr, pos, out);
}